// Round 1
// baseline (268.604 us; speedup 1.0000x reference)
//
#include <hip/hip_runtime.h>
#include <hip/hip_bf16.h>
#include <math.h>

// Problem constants
#define T_ 4
#define N_ 16
#define F_ 6
#define L_ 1024
#define A_ 21
#define K_ 20
#define U_ 256
#define LOUT 1005            // L - K + 1
#define NIMG 384             // T*N*F
#define SZ_S (T_*N_*U_)      // 16384
#define SZ_R (K_*A_*U_)      // 107520

typedef __attribute__((ext_vector_type(8))) short short8;   // 8 bf16 (4 VGPR)
typedef __attribute__((ext_vector_type(4))) float f32x4;    // 4 f32 acc

__device__ __forceinline__ unsigned short f2bf(float f) {
  unsigned int u = __float_as_uint(f);
  u += 0x7FFFu + ((u >> 16) & 1u);   // round to nearest even
  return (unsigned short)(u >> 16);
}

// float atomic max via int/uint atomics (correct for all sign combos; init -inf)
__device__ __forceinline__ void atomicMaxF(float* addr, float val) {
  if (val >= 0.f) atomicMax((int*)addr, __float_as_int(val));
  else            atomicMin((unsigned int*)addr, __float_as_uint(val));
}

// Computes: S init to -inf, R (fp32, exact) into d_out, and Rt = bf16 R
// transposed+padded to [kk][u][32] in workspace for the MFMA B operand.
__global__ void prep_kernel(const float* __restrict__ P_logit,
                            const float* __restrict__ Q,
                            float* __restrict__ out,
                            unsigned short* __restrict__ Rt) {
  int tid = blockIdx.x * blockDim.x + threadIdx.x;
  if (tid < SZ_S) out[tid] = -INFINITY;          // S init for atomic max
  if (tid >= K_ * U_) return;
  int k = tid / U_;
  int u = tid - k * U_;
  const float* pl = P_logit + (size_t)k * A_ * U_ + u;
  float v[A_];
  float m = -INFINITY;
#pragma unroll
  for (int a = 0; a < A_; ++a) { v[a] = pl[(size_t)a * U_]; m = fmaxf(m, v[a]); }
  float s = 0.f;
#pragma unroll
  for (int a = 0; a < A_; ++a) { v[a] = expf(v[a] - m); s += v[a]; }
  float qs = 0.f;
#pragma unroll
  for (int a = 0; a < A_; ++a) qs += Q[a];
  float eps = qs * (1.0f / A_);
  float invs = 1.f / s;
  float* Rout = out + SZ_S;
  unsigned short* rt = Rt + (size_t)(k * U_ + u) * 32;
#pragma unroll
  for (int a = 0; a < A_; ++a) {
    float r = logf(fmaxf(v[a] * invs / Q[a], eps));
    Rout[(size_t)(k * A_ + a) * U_ + u] = r;     // fp32 R output
    rt[a] = f2bf(r);                             // bf16 B-matrix
  }
#pragma unroll
  for (int a = A_; a < 32; ++a) rt[a] = 0;       // zero pad K 21->32
}

// Conv as 20 accumulated GEMMs (one per tap kk), each one MFMA K-step (21->32).
// Block tile: 128 l x 128 u, 4 waves (2x2), wave tile 64x64 (4x4 16x16 frags).
// X window for the whole block staged ONCE in LDS (serves all 20 taps).
#define BM 128
#define WROWS (BM + K_ - 1)   // 147

__global__ __launch_bounds__(256) void conv_kernel(
    const float* __restrict__ X,
    const unsigned short* __restrict__ Rt,
    float* __restrict__ out) {
  __shared__ unsigned short Xs[WROWS][32];   // bf16, 21 valid a + zero pad
  const int n  = blockIdx.z;
  const int l0 = blockIdx.y * BM;
  const int u0 = blockIdx.x * 128;

  // Stage X window [l0 .. l0+146] x [0..20] -> LDS bf16 (pad a to 32, guard l)
  const float* Xn = X + (size_t)n * (L_ * A_);
  for (int idx = threadIdx.x; idx < WROWS * 32; idx += 256) {
    int r = idx >> 5, c = idx & 31;
    int l = l0 + r;
    float v = (c < A_ && l < L_) ? Xn[l * A_ + c] : 0.f;
    Xs[r][c] = f2bf(v);
  }
  __syncthreads();

  const int wid  = threadIdx.x >> 6;
  const int lane = threadIdx.x & 63;
  const int wm   = wid >> 1;            // wave row (0..1)
  const int wn   = wid & 1;             // wave col (0..1)
  const int lr   = lane & 15;           // frag row (A) / col (B,C)
  const int lk   = (lane >> 4) << 3;    // frag k-offset (a dim)

  f32x4 acc[4][4];
#pragma unroll
  for (int mt = 0; mt < 4; ++mt)
#pragma unroll
    for (int nt = 0; nt < 4; ++nt)
      acc[mt][nt] = (f32x4){0.f, 0.f, 0.f, 0.f};

  const unsigned short* rb = Rt + ((size_t)(u0 + wn * 64 + lr)) * 32 + lk;

  for (int kk = 0; kk < K_; ++kk) {
    short8 bfr[4], afr[4];
    const unsigned short* rbk = rb + (size_t)kk * (U_ * 32);
#pragma unroll
    for (int nt = 0; nt < 4; ++nt)
      bfr[nt] = *(const short8*)(rbk + nt * (16 * 32));   // 16B, L2-hit
    const int ar = wm * 64 + lr + kk;
#pragma unroll
    for (int mt = 0; mt < 4; ++mt)
      afr[mt] = *(const short8*)(&Xs[ar + mt * 16][lk]);  // ds_read_b128
#pragma unroll
    for (int mt = 0; mt < 4; ++mt)
#pragma unroll
      for (int nt = 0; nt < 4; ++nt)
        acc[mt][nt] = __builtin_amdgcn_mfma_f32_16x16x32_bf16(
            afr[mt], bfr[nt], acc[mt][nt], 0, 0, 0);
  }

  // Epilogue: Z write (C/D layout: col=lane&15, row=(lane>>4)*4+reg) + fused S max
  float* Z = out + SZ_S + SZ_R;
  const int ucol = u0 + wn * 64 + lr;
  float pmax[4] = {-INFINITY, -INFINITY, -INFINITY, -INFINITY};

#pragma unroll
  for (int mt = 0; mt < 4; ++mt) {
    const int lb = l0 + wm * 64 + mt * 16 + ((lane >> 4) << 2);
#pragma unroll
    for (int reg = 0; reg < 4; ++reg) {
      const int l = lb + reg;
      if (l < LOUT) {
        float* zrow = Z + ((size_t)n * LOUT + l) * U_ + ucol;
#pragma unroll
        for (int nt = 0; nt < 4; ++nt) {
          float v = acc[mt][nt][reg];
          zrow[nt * 16] = v;
          pmax[nt] = fmaxf(pmax[nt], v);
        }
      }
    }
  }

  // Reduce max over the wave's 64 rows (lane groups differ in row only)
#pragma unroll
  for (int off = 16; off < 64; off <<= 1)
#pragma unroll
    for (int nt = 0; nt < 4; ++nt)
      pmax[nt] = fmaxf(pmax[nt], __shfl_xor(pmax[nt], off));

  if (lane < 16) {
    const int tn = n / F_;   // t*16 + nn
    float* Sp = out + (size_t)tn * U_ + u0 + wn * 64 + lane;
#pragma unroll
    for (int nt = 0; nt < 4; ++nt)
      atomicMaxF(Sp + nt * 16, pmax[nt]);
  }
}

extern "C" void kernel_launch(void* const* d_in, const int* in_sizes, int n_in,
                              void* d_out, int out_size, void* d_ws, size_t ws_size,
                              hipStream_t stream) {
  const float* X       = (const float*)d_in[0];
  const float* P_logit = (const float*)d_in[1];
  const float* Q       = (const float*)d_in[2];
  float* out = (float*)d_out;
  unsigned short* Rt = (unsigned short*)d_ws;   // K_*U_*32*2 = 320 KB

  hipLaunchKernelGGL(prep_kernel, dim3(64), dim3(256), 0, stream,
                     P_logit, Q, out, Rt);
  dim3 grid(2, 8, NIMG);   // u-tiles, l-tiles, images
  hipLaunchKernelGGL(conv_kernel, grid, dim3(256), 0, stream, X, Rt, out);
}

// Round 2
// 258.810 us; speedup vs baseline: 1.0378x; 1.0378x over previous
//
#include <hip/hip_runtime.h>
#include <hip/hip_bf16.h>
#include <math.h>

// Problem constants
#define T_ 4
#define N_ 16
#define F_ 6
#define L_ 1024
#define A_ 21
#define K_ 20
#define U_ 256
#define LOUT 1005            // L - K + 1
#define NIMG 384             // T*N*F
#define SZ_S (T_*N_*U_)      // 16384
#define SZ_R (K_*A_*U_)      // 107520

typedef __attribute__((ext_vector_type(8))) short short8;   // 8 bf16 (4 VGPR)
typedef __attribute__((ext_vector_type(4))) float f32x4;    // 4 f32 acc

__device__ __forceinline__ unsigned short f2bf(float f) {
  unsigned int u = __float_as_uint(f);
  u += 0x7FFFu + ((u >> 16) & 1u);   // round to nearest even
  return (unsigned short)(u >> 16);
}

// float atomic max via int/uint atomics (correct for all sign combos; init -inf)
__device__ __forceinline__ void atomicMaxF(float* addr, float val) {
  if (val >= 0.f) atomicMax((int*)addr, __float_as_int(val));
  else            atomicMin((unsigned int*)addr, __float_as_uint(val));
}

// Computes: S init to -inf, R (fp32, exact) into d_out, and Rt = bf16 R
// transposed+padded to [kk][u][32] in workspace for the MFMA A operand.
__global__ void prep_kernel(const float* __restrict__ P_logit,
                            const float* __restrict__ Q,
                            float* __restrict__ out,
                            unsigned short* __restrict__ Rt) {
  int tid = blockIdx.x * blockDim.x + threadIdx.x;
  if (tid < SZ_S) out[tid] = -INFINITY;          // S init for atomic max
  if (tid >= K_ * U_) return;
  int k = tid / U_;
  int u = tid - k * U_;
  const float* pl = P_logit + (size_t)k * A_ * U_ + u;
  float v[A_];
  float m = -INFINITY;
#pragma unroll
  for (int a = 0; a < A_; ++a) { v[a] = pl[(size_t)a * U_]; m = fmaxf(m, v[a]); }
  float s = 0.f;
#pragma unroll
  for (int a = 0; a < A_; ++a) { v[a] = expf(v[a] - m); s += v[a]; }
  float qs = 0.f;
#pragma unroll
  for (int a = 0; a < A_; ++a) qs += Q[a];
  float eps = qs * (1.0f / A_);
  float invs = 1.f / s;
  float* Rout = out + SZ_S;
  unsigned short* rt = Rt + (size_t)(k * U_ + u) * 32;
#pragma unroll
  for (int a = 0; a < A_; ++a) {
    float r = logf(fmaxf(v[a] * invs / Q[a], eps));
    Rout[(size_t)(k * A_ + a) * U_ + u] = r;     // fp32 R output
    rt[a] = f2bf(r);                             // bf16 A-matrix
  }
#pragma unroll
  for (int a = A_; a < 32; ++a) rt[a] = 0;       // zero pad K 21->32
}

// Conv as 20 accumulated GEMMs (one per tap kk), each one MFMA K-step (21->32).
// SWAPPED operands vs round 1: A = R (M = u), B = X (N = l)  =>  D tile is
// Z[u][l]; each lane holds 4 CONSECUTIVE u at fixed l -> float4 stores.
// Block tile: 128 l x 128 u, 4 waves (2x2), wave tile 64u x 64l.
// X window for the whole block staged ONCE in LDS (serves all 20 taps).
#define BM 128
#define WROWS (BM + K_ - 1)   // 147
#define XSTR 40               // LDS row stride in shorts (80 B): 2-way banks = free

__global__ __launch_bounds__(256, 4) void conv_kernel(
    const float* __restrict__ X,
    const unsigned short* __restrict__ Rt,
    float* __restrict__ out) {
  __shared__ unsigned short Xs[WROWS * XSTR];   // 11760 B
  const int n  = blockIdx.z;
  const int l0 = blockIdx.y * BM;
  const int u0 = blockIdx.x * 128;

  // Stage X window [l0 .. l0+146] x [0..20] -> LDS bf16 (pad a to 32, guard l)
  const float* Xn = X + (size_t)n * (L_ * A_);
  for (int idx = threadIdx.x; idx < WROWS * 32; idx += 256) {
    int r = idx >> 5, c = idx & 31;
    int l = l0 + r;
    float v = (c < A_ && l < L_) ? Xn[l * A_ + c] : 0.f;
    Xs[r * XSTR + c] = f2bf(v);
  }
  __syncthreads();

  const int wid  = threadIdx.x >> 6;
  const int lane = threadIdx.x & 63;
  const int wl   = wid >> 1;            // wave l position (0..1)
  const int wu   = wid & 1;             // wave u position (0..1)
  const int fl   = lane & 15;           // frag row (A: u) / col (B: l)
  const int fk   = (lane >> 4) << 3;    // frag k-offset (a dim)

  f32x4 acc[4][4];                      // [ut][lt]
#pragma unroll
  for (int ut = 0; ut < 4; ++ut)
#pragma unroll
    for (int lt = 0; lt < 4; ++lt)
      acc[ut][lt] = (f32x4){0.f, 0.f, 0.f, 0.f};

  const unsigned short* rbase = Rt + ((size_t)(u0 + wu * 64 + fl)) * 32 + fk;
  const int arow = wl * 64 + fl;        // base X row in window

  short8 rcur[4];
#pragma unroll
  for (int ut = 0; ut < 4; ++ut)
    rcur[ut] = *(const short8*)(rbase + ut * (16 * 32));

  for (int kk = 0; kk < K_; ++kk) {
    short8 xfr[4];
#pragma unroll
    for (int lt = 0; lt < 4; ++lt)
      xfr[lt] = *(const short8*)(&Xs[(arow + lt * 16 + kk) * XSTR + fk]);
    // prefetch next tap's R fragments (clamped; last iter re-reads valid mem)
    const int kn = (kk + 1 < K_) ? kk + 1 : K_ - 1;
    short8 rnxt[4];
    const unsigned short* rbk = rbase + (size_t)kn * (U_ * 32);
#pragma unroll
    for (int ut = 0; ut < 4; ++ut)
      rnxt[ut] = *(const short8*)(rbk + ut * (16 * 32));
#pragma unroll
    for (int ut = 0; ut < 4; ++ut)
#pragma unroll
      for (int lt = 0; lt < 4; ++lt)
        acc[ut][lt] = __builtin_amdgcn_mfma_f32_16x16x32_bf16(
            rcur[ut], xfr[lt], acc[ut][lt], 0, 0, 0);
#pragma unroll
    for (int ut = 0; ut < 4; ++ut) rcur[ut] = rnxt[ut];
  }

  // Epilogue: D layout col(l)=lane&15, row(u)=(lane>>4)*4+reg -> lane holds
  // 4 consecutive u at fixed l => float4 store into row-major Z[l][u].
  float* Z = out + SZ_S + SZ_R;
  const int ug = (lane >> 4) << 2;      // u offset within frag (0,4,8,12)
  float pmax[4][4];                     // [ut][reg]
#pragma unroll
  for (int ut = 0; ut < 4; ++ut)
#pragma unroll
    for (int r = 0; r < 4; ++r) pmax[ut][r] = -INFINITY;

#pragma unroll
  for (int lt = 0; lt < 4; ++lt) {
    const int l = l0 + wl * 64 + lt * 16 + fl;
    if (l < LOUT) {
      float* zrow = Z + ((size_t)n * LOUT + l) * U_ + u0 + wu * 64 + ug;
#pragma unroll
      for (int ut = 0; ut < 4; ++ut) {
        f32x4 v = acc[ut][lt];
        __builtin_nontemporal_store(v, (f32x4*)(zrow + ut * 16));
#pragma unroll
        for (int r = 0; r < 4; ++r) pmax[ut][r] = fmaxf(pmax[ut][r], v[r]);
      }
    }
  }

  // Reduce max over l within the frag (lanes differing in lane&15)
#pragma unroll
  for (int off = 1; off < 16; off <<= 1)
#pragma unroll
    for (int ut = 0; ut < 4; ++ut)
#pragma unroll
      for (int r = 0; r < 4; ++r)
        pmax[ut][r] = fmaxf(pmax[ut][r], __shfl_xor(pmax[ut][r], off));

  if (fl == 0) {
    const int tn = n / F_;   // t*16 + nn
    float* Sp = out + (size_t)tn * U_ + u0 + wu * 64 + ug;
#pragma unroll
    for (int ut = 0; ut < 4; ++ut)
#pragma unroll
      for (int r = 0; r < 4; ++r)
        atomicMaxF(Sp + ut * 16 + r, pmax[ut][r]);
  }
}

extern "C" void kernel_launch(void* const* d_in, const int* in_sizes, int n_in,
                              void* d_out, int out_size, void* d_ws, size_t ws_size,
                              hipStream_t stream) {
  const float* X       = (const float*)d_in[0];
  const float* P_logit = (const float*)d_in[1];
  const float* Q       = (const float*)d_in[2];
  float* out = (float*)d_out;
  unsigned short* Rt = (unsigned short*)d_ws;   // K_*U_*32*2 = 320 KB

  hipLaunchKernelGGL(prep_kernel, dim3(64), dim3(256), 0, stream,
                     P_logit, Q, out, Rt);
  dim3 grid(2, 8, NIMG);   // u-tiles, l-tiles, images
  hipLaunchKernelGGL(conv_kernel, grid, dim3(256), 0, stream, X, Rt, out);
}